// Round 4
// baseline (1074.005 us; speedup 1.0000x reference)
//
#include <hip/hip_runtime.h>
#include <hip/hip_bf16.h>
#include <math.h>

#define M_DIM 32768
#define K_DIM 2048
#define N_DIM 2048
#define NBLK (N_DIM / 128)   // 16 n-blocks

typedef __attribute__((ext_vector_type(8))) short short8;   // 8 bf16 = 4 VGPRs
typedef __attribute__((ext_vector_type(4))) float floatx4;  // MFMA C/D

// fp32 -> bf16 bits, round-to-nearest-even
static __device__ __forceinline__ unsigned short f2bf(float f) {
    unsigned u = __builtin_bit_cast(unsigned, f);
    unsigned r = (u + 0x7FFFu + ((u >> 16) & 1u)) >> 16;
    return (unsigned short)r;
}

// ---------------------------------------------------------------------------
// Fused GEMM(+bias) + per-128-col-block (rowmax, sumexp) partials.
// INPUTS ARE FLOAT32 (fp16 promoted by harness — round-3 forensics: junk
// low-halves capped at ±2^65 produced the exact observed 3.2466e21).
// Structure: 128x128 tile, BK=32, 4 waves (2x2), 4x4 16x16x32 bf16 MFMA.
// Staging: fp32 global loads -> f2bf -> ds_write_b128.
// ---------------------------------------------------------------------------
__global__ __launch_bounds__(256) void gemm_lse(const float* __restrict__ x,
                                                const float* __restrict__ W,
                                                const float* __restrict__ bias,
                                                float2* __restrict__ part) {
    __shared__ unsigned short lds_a[128 * 32];  // [m][k] row-major bf16 bits
    __shared__ unsigned short lds_b[128 * 32];  // [n][k] row-major bf16 bits
    __shared__ float red[2][128][2];            // [col-half][row][max,sum]

    const int t    = threadIdx.x;
    const int w    = t >> 6;     // wave 0..3
    const int l    = t & 63;
    const int quad = l >> 4;     // 0..3
    const int lrow = l & 15;
    const int m0   = blockIdx.y * 128;
    const int n0   = blockIdx.x * 128;
    const int wm   = (w >> 1) * 64;  // wave's m-offset in tile
    const int wn   = (w & 1) * 64;   // wave's n-offset in tile

    floatx4 acc[4][4] = {};  // acc[im][in]

    // A staging: thread t covers row ar = t>>1, k in [ah, ah+16), ah = 16*(t&1)
    const int ar = t >> 1, ah = (t & 1) * 16;
    const float* gx = x + (size_t)(m0 + ar) * K_DIM + ah;
    // B staging: thread t covers n = t&127, k in [bh, bh+16), bh = 16*(t>>7)
    const int bn = t & 127, bh = (t >> 7) * 16;
    const float* gw = W + (size_t)bh * N_DIM + n0 + bn;

    for (int kt = 0; kt < K_DIM; kt += 32) {
        // ---- global fp32 loads into registers (before barrier)
        float4 xa[4];
#pragma unroll
        for (int q = 0; q < 4; ++q)
            xa[q] = *(const float4*)(gx + kt + q * 4);
        float wv[16];
#pragma unroll
        for (int j = 0; j < 16; ++j)
            wv[j] = gw[(size_t)(kt + j) * N_DIM];

        // ---- convert to bf16, pack
        short8 pa0, pa1, pb0, pb1;
#pragma unroll
        for (int j = 0; j < 4; ++j) {
            pa0[j]     = (short)f2bf(((const float*)&xa[0])[j]);
            pa0[j + 4] = (short)f2bf(((const float*)&xa[1])[j]);
            pa1[j]     = (short)f2bf(((const float*)&xa[2])[j]);
            pa1[j + 4] = (short)f2bf(((const float*)&xa[3])[j]);
        }
#pragma unroll
        for (int j = 0; j < 8; ++j) {
            pb0[j] = (short)f2bf(wv[j]);
            pb1[j] = (short)f2bf(wv[j + 8]);
        }

        __syncthreads();  // all waves done reading LDS from previous iter
        *(short8*)&lds_a[ar * 32 + ah]     = pa0;
        *(short8*)&lds_a[ar * 32 + ah + 8] = pa1;
        *(short8*)&lds_b[bn * 32 + bh]     = pb0;
        *(short8*)&lds_b[bn * 32 + bh + 8] = pb1;
        __syncthreads();  // writes visible to all waves

        // Fragments: lane holds Op[16dim = lrow][k = quad*8 + j], k-contiguous
        short8 af[4], bf[4];
#pragma unroll
        for (int im = 0; im < 4; ++im)
            af[im] = *(const short8*)((const char*)lds_a + (wm + im * 16 + lrow) * 64 + quad * 16);
#pragma unroll
        for (int in = 0; in < 4; ++in)
            bf[in] = *(const short8*)((const char*)lds_b + (wn + in * 16 + lrow) * 64 + quad * 16);
#pragma unroll
        for (int im = 0; im < 4; ++im)
#pragma unroll
            for (int in = 0; in < 4; ++in)
                acc[im][in] = __builtin_amdgcn_mfma_f32_16x16x32_bf16(af[im], bf[in], acc[im][in], 0, 0, 0);
    }

    // ---- Epilogue: bias add + per-row (max, sumexp) over this block's 128 cols
    // C/D layout: col = lrow (n), row = quad*4 + reg (m)  [m89/m91-verified]
    float bv[4];
#pragma unroll
    for (int in = 0; in < 4; ++in)
        bv[in] = bias[n0 + wn + in * 16 + lrow];

#pragma unroll
    for (int im = 0; im < 4; ++im) {
#pragma unroll
        for (int r = 0; r < 4; ++r) {
            float v0 = acc[im][0][r] + bv[0];
            float v1 = acc[im][1][r] + bv[1];
            float v2 = acc[im][2][r] + bv[2];
            float v3 = acc[im][3][r] + bv[3];
            float mx = fmaxf(fmaxf(v0, v1), fmaxf(v2, v3));
#pragma unroll
            for (int s = 1; s < 16; s <<= 1)
                mx = fmaxf(mx, __shfl_xor(mx, s, 64));
            float sm = __expf(v0 - mx) + __expf(v1 - mx) + __expf(v2 - mx) + __expf(v3 - mx);
#pragma unroll
            for (int s = 1; s < 16; s <<= 1)
                sm += __shfl_xor(sm, s, 64);
            if (lrow == im * 4 + r) {  // one writer per (im, r) among 16 lanes
                int row = wm + im * 16 + quad * 4 + r;
                red[w & 1][row][0] = mx;
                red[w & 1][row][1] = sm;
            }
        }
    }
    __syncthreads();
    if (t < 128) {
        float ma = red[0][t][0], sa = red[0][t][1];
        float mb = red[1][t][0], sb = red[1][t][1];
        float mm = fmaxf(ma, mb);
        float ss = sa * __expf(ma - mm) + sb * __expf(mb - mm);
        part[(size_t)blockIdx.x * M_DIM + m0 + t] = make_float2(mm, ss);
    }
}

// ---------------------------------------------------------------------------
// Merge NBLK partials per row, logsumexp, leaky x2, erf-GELU x2. FLOAT out.
// Tripwires kept (inert when correct: mm finite, ss >= 1).
// ---------------------------------------------------------------------------
__global__ __launch_bounds__(256) void lse_final(const float2* __restrict__ part,
                                                 float* __restrict__ out) {
    const int r = blockIdx.x * 256 + threadIdx.x;
    float2 p[NBLK];
    float mm = -INFINITY;
#pragma unroll
    for (int nb = 0; nb < NBLK; ++nb) {
        p[nb] = part[(size_t)nb * M_DIM + r];
        mm = fmaxf(mm, p[nb].x);
    }
    float ss = 0.f;
#pragma unroll
    for (int nb = 0; nb < NBLK; ++nb)
        ss += p[nb].y * __expf(p[nb].x - mm);

    float z;
    if (isnan(mm)) {
        z = 12345.0f;               // tripwire A
    } else if (!(ss > 0.f)) {
        z = mm;                     // tripwire B
    } else {
        z = mm + logf(ss);
    }
    z = z > 0.f ? z : 0.01f * z;   // leaky_relu
    z = z > 0.f ? z : 0.01f * z;   // leaky_relu
    z = 0.5f * z * (1.f + erff(z * 0.70710678118654752f));  // exact GELU
    z = 0.5f * z * (1.f + erff(z * 0.70710678118654752f));  // exact GELU
    out[r] = z;
}

// ---------------------------------------------------------------------------
extern "C" void kernel_launch(void* const* d_in, const int* in_sizes, int n_in,
                              void* d_out, int out_size, void* d_ws, size_t ws_size,
                              hipStream_t stream) {
    // Harness promotes float16 reference tensors to float32 (round-3 forensics).
    const float* x    = (const float*)d_in[0];
    const float* W    = (const float*)d_in[1];
    const float* bias = (const float*)d_in[2];
    float* out = (float*)d_out;   // fp16 output -> "else float*"

    // ws layout: [0, 4MB) = partials (NBLK, M) float2
    float2* part = (float2*)d_ws;

    gemm_lse<<<dim3(N_DIM / 128, M_DIM / 128), 256, 0, stream>>>(x, W, bias, part);
    lse_final<<<dim3(M_DIM / 256), 256, 0, stream>>>(part, out);
}

// Round 5
// 724.148 us; speedup vs baseline: 1.4831x; 1.4831x over previous
//
#include <hip/hip_runtime.h>
#include <hip/hip_bf16.h>
#include <math.h>

#define M_DIM 32768
#define K_DIM 2048
#define N_DIM 2048
#define NBLK (N_DIM / 128)   // 16 n-blocks

typedef __attribute__((ext_vector_type(8))) short short8;   // 8 bf16 = 4 VGPRs
typedef __attribute__((ext_vector_type(4))) float floatx4;  // MFMA C/D

typedef __attribute__((address_space(1))) const void global_cv;
typedef __attribute__((address_space(3))) void lds_v;

// fp32 -> bf16 bits, round-to-nearest-even
static __device__ __forceinline__ unsigned short f2bf(float f) {
    unsigned u = __builtin_bit_cast(unsigned, f);
    unsigned r = (u + 0x7FFFu + ((u >> 16) & 1u)) >> 16;
    return (unsigned short)r;
}

// ---------------------------------------------------------------------------
// cvt_x: x fp32 (M,K) -> bf16 bits, 8 elems/thread, fully coalesced.
// ---------------------------------------------------------------------------
__global__ __launch_bounds__(256) void cvt_x(const float* __restrict__ x,
                                             unsigned short* __restrict__ xb) {
    size_t off = ((size_t)blockIdx.x * 256 + threadIdx.x) * 8;
    float4 a = *(const float4*)(x + off);
    float4 b = *(const float4*)(x + off + 4);
    short8 p;
    p[0] = (short)f2bf(a.x); p[1] = (short)f2bf(a.y);
    p[2] = (short)f2bf(a.z); p[3] = (short)f2bf(a.w);
    p[4] = (short)f2bf(b.x); p[5] = (short)f2bf(b.y);
    p[6] = (short)f2bf(b.z); p[7] = (short)f2bf(b.w);
    *(short8*)(xb + off) = p;
}

// ---------------------------------------------------------------------------
// cvt_wt: W fp32 (K,N) -> Wt bf16 (N,K), 64x64 LDS-tiled transpose.
// ---------------------------------------------------------------------------
__global__ __launch_bounds__(256) void cvt_wt(const float* __restrict__ W,
                                              unsigned short* __restrict__ Wt) {
    __shared__ unsigned short tile[64][65];  // +1 pad: odd stride spreads banks
    const int t  = threadIdx.x;
    const int nb = blockIdx.x * 64;
    const int kb = blockIdx.y * 64;
#pragma unroll
    for (int i = 0; i < 16; ++i) {
        int e = i * 256 + t;
        int r = e >> 6, c = e & 63;  // r=k-local, c=n-local (coalesced fp32 read)
        tile[r][c] = f2bf(W[(size_t)(kb + r) * N_DIM + nb + c]);
    }
    __syncthreads();
#pragma unroll
    for (int i = 0; i < 16; ++i) {
        int e = i * 256 + t;
        int r = e >> 6, c = e & 63;  // r=n-local, c=k-local (coalesced write)
        Wt[(size_t)(nb + r) * K_DIM + kb + c] = tile[c][r];
    }
}

// ---------------------------------------------------------------------------
// Fused GEMM(+bias) + per-128-col-block (rowmax, sumexp) partials.
// m97 structure: 128x128 tile, BK=32, 4 waves (2x2), 4x4 16x16x32 bf16 MFMA,
// global_load_lds width=16 staging (validated: rounds 2&3 bit-identical).
// XBF16=true : A from pre-converted xb (bf16), pure global_load_lds.
// XBF16=false: A from fp32 x, in-register f2bf + ds_write (round-4-validated);
//              B still global_load_lds from Wt. (ws too small for xb.)
// ---------------------------------------------------------------------------
template <bool XBF16>
__global__ __launch_bounds__(256) void gemm_lse(const void* __restrict__ xin,
                                                const unsigned short* __restrict__ Wt,
                                                const float* __restrict__ bias,
                                                float2* __restrict__ part) {
    __shared__ unsigned short lds_a[128 * 32];  // [m][k] row-major bf16
    __shared__ unsigned short lds_b[128 * 32];  // [n][k] row-major bf16
    __shared__ float red[2][128][2];            // [col-half][row][max,sum]

    const int t    = threadIdx.x;
    const int w    = t >> 6;
    const int l    = t & 63;
    const int quad = l >> 4;
    const int lrow = l & 15;
    const int m0   = blockIdx.y * 128;
    const int n0   = blockIdx.x * 128;
    const int wm   = (w >> 1) * 64;
    const int wn   = (w & 1) * 64;

    floatx4 acc[4][4] = {};

    // B staging: chunk c=t covers Wt-tile row t>>2, k-off (t&3)*8, lds byte t*16
    const unsigned short* gb = Wt + (size_t)(n0 + (t >> 2)) * K_DIM + (t & 3) * 8;
    char* lb = (char*)&lds_b[0] + t * 16;
    // A staging (fast path): same chunk pattern on xb
    const unsigned short* ga_bf =
        XBF16 ? (const unsigned short*)xin + (size_t)(m0 + (t >> 2)) * K_DIM + (t & 3) * 8 : nullptr;
    char* la = (char*)&lds_a[0] + t * 16;
    // A staging (fallback): thread covers row t>>1, k-half (t&1)*16, fp32
    const int ar = t >> 1, ah = (t & 1) * 16;
    const float* gx_f = XBF16 ? nullptr : (const float*)xin + (size_t)(m0 + ar) * K_DIM + ah;

    for (int kt = 0; kt < K_DIM; kt += 32) {
        if constexpr (XBF16) {
            __builtin_amdgcn_global_load_lds((global_cv*)(ga_bf),              (lds_v*)(la),        16, 0, 0);
            __builtin_amdgcn_global_load_lds((global_cv*)(ga_bf + 64 * K_DIM), (lds_v*)(la + 4096), 16, 0, 0);
            __builtin_amdgcn_global_load_lds((global_cv*)(gb),                 (lds_v*)(lb),        16, 0, 0);
            __builtin_amdgcn_global_load_lds((global_cv*)(gb + 64 * K_DIM),    (lds_v*)(lb + 4096), 16, 0, 0);
            ga_bf += 32;
            gb += 32;
            __syncthreads();  // drains vmcnt -> both tiles deposited
        } else {
            // issue B DMA (prev-iter readers already past loop-end barrier)
            __builtin_amdgcn_global_load_lds((global_cv*)(gb),              (lds_v*)(lb),        16, 0, 0);
            __builtin_amdgcn_global_load_lds((global_cv*)(gb + 64 * K_DIM), (lds_v*)(lb + 4096), 16, 0, 0);
            gb += 32;
            // A fp32 -> bf16 in registers
            float4 xa[4];
#pragma unroll
            for (int q = 0; q < 4; ++q)
                xa[q] = *(const float4*)(gx_f + kt + q * 4);
            short8 pa0, pa1;
#pragma unroll
            for (int j = 0; j < 4; ++j) {
                pa0[j]     = (short)f2bf(((const float*)&xa[0])[j]);
                pa0[j + 4] = (short)f2bf(((const float*)&xa[1])[j]);
                pa1[j]     = (short)f2bf(((const float*)&xa[2])[j]);
                pa1[j + 4] = (short)f2bf(((const float*)&xa[3])[j]);
            }
            __syncthreads();  // prev-iter reads done; vmcnt drained (B ready)
            *(short8*)&lds_a[ar * 32 + ah]     = pa0;
            *(short8*)&lds_a[ar * 32 + ah + 8] = pa1;
            __syncthreads();  // A writes visible
        }

        short8 af[4], bf[4];
#pragma unroll
        for (int im = 0; im < 4; ++im)
            af[im] = *(const short8*)((const char*)lds_a + (wm + im * 16 + lrow) * 64 + quad * 16);
#pragma unroll
        for (int in = 0; in < 4; ++in)
            bf[in] = *(const short8*)((const char*)lds_b + (wn + in * 16 + lrow) * 64 + quad * 16);
#pragma unroll
        for (int im = 0; im < 4; ++im)
#pragma unroll
            for (int in = 0; in < 4; ++in)
                acc[im][in] = __builtin_amdgcn_mfma_f32_16x16x32_bf16(af[im], bf[in], acc[im][in], 0, 0, 0);
        __syncthreads();  // protect LDS before next iter's deposits
    }

    // ---- Epilogue (round-4-validated): C/D layout col=lrow(n), row=quad*4+reg(m)
    float bv[4];
#pragma unroll
    for (int in = 0; in < 4; ++in)
        bv[in] = bias[n0 + wn + in * 16 + lrow];

#pragma unroll
    for (int im = 0; im < 4; ++im) {
#pragma unroll
        for (int r = 0; r < 4; ++r) {
            float v0 = acc[im][0][r] + bv[0];
            float v1 = acc[im][1][r] + bv[1];
            float v2 = acc[im][2][r] + bv[2];
            float v3 = acc[im][3][r] + bv[3];
            float mx = fmaxf(fmaxf(v0, v1), fmaxf(v2, v3));
#pragma unroll
            for (int s = 1; s < 16; s <<= 1)
                mx = fmaxf(mx, __shfl_xor(mx, s, 64));
            float sm = __expf(v0 - mx) + __expf(v1 - mx) + __expf(v2 - mx) + __expf(v3 - mx);
#pragma unroll
            for (int s = 1; s < 16; s <<= 1)
                sm += __shfl_xor(sm, s, 64);
            if (lrow == im * 4 + r) {
                int row = wm + im * 16 + quad * 4 + r;
                red[w & 1][row][0] = mx;
                red[w & 1][row][1] = sm;
            }
        }
    }
    __syncthreads();
    if (t < 128) {
        float ma = red[0][t][0], sa = red[0][t][1];
        float mb = red[1][t][0], sb = red[1][t][1];
        float mm = fmaxf(ma, mb);
        float ss = sa * __expf(ma - mm) + sb * __expf(mb - mm);
        part[(size_t)blockIdx.x * M_DIM + m0 + t] = make_float2(mm, ss);
    }
}

// ---------------------------------------------------------------------------
// Merge NBLK partials per row, logsumexp, leaky x2, erf-GELU x2. FLOAT out.
// ---------------------------------------------------------------------------
__global__ __launch_bounds__(256) void lse_final(const float2* __restrict__ part,
                                                 float* __restrict__ out) {
    const int r = blockIdx.x * 256 + threadIdx.x;
    float2 p[NBLK];
    float mm = -INFINITY;
#pragma unroll
    for (int nb = 0; nb < NBLK; ++nb) {
        p[nb] = part[(size_t)nb * M_DIM + r];
        mm = fmaxf(mm, p[nb].x);
    }
    float ss = 0.f;
#pragma unroll
    for (int nb = 0; nb < NBLK; ++nb)
        ss += p[nb].y * __expf(p[nb].x - mm);

    float z;
    if (isnan(mm)) {
        z = 12345.0f;               // tripwire A (inert when correct)
    } else if (!(ss > 0.f)) {
        z = mm;                     // tripwire B (inert when correct)
    } else {
        z = mm + logf(ss);
    }
    z = z > 0.f ? z : 0.01f * z;
    z = z > 0.f ? z : 0.01f * z;
    z = 0.5f * z * (1.f + erff(z * 0.70710678118654752f));
    z = 0.5f * z * (1.f + erff(z * 0.70710678118654752f));
    out[r] = z;
}

// ---------------------------------------------------------------------------
extern "C" void kernel_launch(void* const* d_in, const int* in_sizes, int n_in,
                              void* d_out, int out_size, void* d_ws, size_t ws_size,
                              hipStream_t stream) {
    const float* x    = (const float*)d_in[0];
    const float* W    = (const float*)d_in[1];
    const float* bias = (const float*)d_in[2];
    float* out = (float*)d_out;

    const size_t xb_bytes   = (size_t)M_DIM * K_DIM * 2;  // 134 MB
    const size_t wt_bytes   = (size_t)N_DIM * K_DIM * 2;  //   8 MB
    const size_t part_bytes = (size_t)NBLK * M_DIM * 8;   //   4 MB

    if (ws_size >= xb_bytes + wt_bytes + part_bytes) {
        // fast path: pre-convert both operands to bf16
        unsigned short* xb = (unsigned short*)d_ws;
        unsigned short* Wt = (unsigned short*)((char*)d_ws + xb_bytes);
        float2* part = (float2*)((char*)d_ws + xb_bytes + wt_bytes);
        cvt_x<<<(int)((size_t)M_DIM * K_DIM / (8 * 256)), 256, 0, stream>>>(x, xb);
        cvt_wt<<<dim3(N_DIM / 64, K_DIM / 64), 256, 0, stream>>>(W, Wt);
        gemm_lse<true><<<dim3(N_DIM / 128, M_DIM / 128), 256, 0, stream>>>(xb, Wt, bias, part);
        lse_final<<<M_DIM / 256, 256, 0, stream>>>(part, out);
    } else {
        // fallback (ws >= 12 MB validated in round 2): Wt only, x converted in-kernel
        unsigned short* Wt = (unsigned short*)d_ws;
        float2* part = (float2*)((char*)d_ws + wt_bytes);
        cvt_wt<<<dim3(N_DIM / 64, K_DIM / 64), 256, 0, stream>>>(W, Wt);
        gemm_lse<false><<<dim3(N_DIM / 128, M_DIM / 128), 256, 0, stream>>>(x, Wt, bias, part);
        lse_final<<<M_DIM / 256, 256, 0, stream>>>(part, out);
    }
}

// Round 6
// 720.346 us; speedup vs baseline: 1.4910x; 1.0053x over previous
//
#include <hip/hip_runtime.h>
#include <hip/hip_bf16.h>
#include <math.h>

#define M_DIM 32768
#define K_DIM 2048
#define N_DIM 2048
#define NBLK (N_DIM / 128)   // 16 n-blocks

typedef __attribute__((ext_vector_type(8))) short short8;   // 8 bf16 = 4 VGPRs
typedef __attribute__((ext_vector_type(4))) float floatx4;  // MFMA C/D

typedef __attribute__((address_space(1))) const void global_cv;
typedef __attribute__((address_space(3))) void lds_v;

// fp32 -> bf16 bits, round-to-nearest-even
static __device__ __forceinline__ unsigned short f2bf(float f) {
    unsigned u = __builtin_bit_cast(unsigned, f);
    unsigned r = (u + 0x7FFFu + ((u >> 16) & 1u)) >> 16;
    return (unsigned short)r;
}

// ---------------------------------------------------------------------------
// cvt_x: x fp32 (M,K) -> bf16 bits, 8 elems/thread, fully coalesced.
// ---------------------------------------------------------------------------
__global__ __launch_bounds__(256) void cvt_x(const float* __restrict__ x,
                                             unsigned short* __restrict__ xb) {
    size_t off = ((size_t)blockIdx.x * 256 + threadIdx.x) * 8;
    float4 a = *(const float4*)(x + off);
    float4 b = *(const float4*)(x + off + 4);
    short8 p;
    p[0] = (short)f2bf(a.x); p[1] = (short)f2bf(a.y);
    p[2] = (short)f2bf(a.z); p[3] = (short)f2bf(a.w);
    p[4] = (short)f2bf(b.x); p[5] = (short)f2bf(b.y);
    p[6] = (short)f2bf(b.z); p[7] = (short)f2bf(b.w);
    *(short8*)(xb + off) = p;
}

// ---------------------------------------------------------------------------
// cvt_wt: W fp32 (K,N) -> Wt bf16 (N,K), 64x64 LDS-tiled transpose.
// ---------------------------------------------------------------------------
__global__ __launch_bounds__(256) void cvt_wt(const float* __restrict__ W,
                                              unsigned short* __restrict__ Wt) {
    __shared__ unsigned short tile[64][65];
    const int t  = threadIdx.x;
    const int nb = blockIdx.x * 64;
    const int kb = blockIdx.y * 64;
#pragma unroll
    for (int i = 0; i < 16; ++i) {
        int e = i * 256 + t;
        int r = e >> 6, c = e & 63;
        tile[r][c] = f2bf(W[(size_t)(kb + r) * N_DIM + nb + c]);
    }
    __syncthreads();
#pragma unroll
    for (int i = 0; i < 16; ++i) {
        int e = i * 256 + t;
        int r = e >> 6, c = e & 63;
        Wt[(size_t)(nb + r) * K_DIM + kb + c] = tile[c][r];
    }
}

// ---------------------------------------------------------------------------
// Fused GEMM(+bias) + per-128-col-block (rowmax, sumexp) partials.
// Round-6 changes vs validated round-5 kernel:
//  * BK=64 (32 iters, 8 DMAs in flight per drain instead of 4) — halves the
//    structural vmcnt(0)+barrier drains.
//  * XOR chunk swizzle: LDS position (row, pk) holds global k-chunk
//    pk ^ (row&7). Realized on the DEPOSIT side by permuting each lane's
//    global source address (global_load_lds deposits lane i at base+i*16,
//    so layout control must come from the source). Fragment reads then hit
//    addr = row*128 + ((s*4+quad)^(lrow&7))*16: within any 8 consecutive
//    lanes all 8 16B-chunk positions (32 banks) are covered exactly once
//    -> conflict-free.
//  * red[] aliased over lds_a (used only post-loop, after barrier): 32 KB LDS.
// ---------------------------------------------------------------------------
__global__ __launch_bounds__(256) void gemm_lse(const unsigned short* __restrict__ xb,
                                                const unsigned short* __restrict__ Wt,
                                                const float* __restrict__ bias,
                                                float2* __restrict__ part) {
    __shared__ char smem[32768];
    unsigned short* lds_a = (unsigned short*)smem;            // [128][64] swizzled
    unsigned short* lds_b = (unsigned short*)(smem + 16384);  // [128][64] swizzled
    float* redf = (float*)smem;  // [2][128][2], epilogue only (post-barrier alias)

    const int t    = threadIdx.x;
    const int w    = t >> 6;
    const int l    = t & 63;
    const int quad = l >> 4;
    const int lrow = l & 15;
    const int m0   = blockIdx.y * 128;
    const int n0   = blockIdx.x * 128;
    const int wm   = (w >> 1) * 64;
    const int wn   = (w & 1) * 64;

    floatx4 acc[4][4] = {};

    // Deposit geometry: round r, lane t -> LDS chunk c = r*256+t at byte c*16,
    // i.e. position (prow, pk) = (r*32 + (t>>3), t&7). Source = global chunk
    // (prow, pk ^ (prow&7))  [prow&7 == (t>>3)&7, r-invariant].
    const int prow = t >> 3;
    const int pk   = (t & 7) ^ (prow & 7);
    const unsigned short* ga = xb + (size_t)(m0 + prow) * K_DIM + pk * 8;
    const unsigned short* gb = Wt + (size_t)(n0 + prow) * K_DIM + pk * 8;
    char* la = (char*)lds_a + t * 16;
    char* lb = (char*)lds_b + t * 16;

    // Fragment read bases (lane-invariant across iters):
    // addr(im, s) = (wm+im*16+lrow)*128 + ((s*4+quad)^(lrow&7))*16
    const int e = lrow & 7;
    const int koff0 = ((quad) ^ e) * 16;
    const int koff1 = ((quad + 4) ^ e) * 16;
    const char* abase[4];
    const char* bbase[4];
#pragma unroll
    for (int i = 0; i < 4; ++i) {
        abase[i] = (const char*)lds_a + (wm + i * 16 + lrow) * 128;
        bbase[i] = (const char*)lds_b + (wn + i * 16 + lrow) * 128;
    }

    for (int kt = 0; kt < K_DIM; kt += 64) {
#pragma unroll
        for (int r = 0; r < 4; ++r)
            __builtin_amdgcn_global_load_lds((global_cv*)(ga + (size_t)r * 32 * K_DIM),
                                             (lds_v*)(la + r * 4096), 16, 0, 0);
#pragma unroll
        for (int r = 0; r < 4; ++r)
            __builtin_amdgcn_global_load_lds((global_cv*)(gb + (size_t)r * 32 * K_DIM),
                                             (lds_v*)(lb + r * 4096), 16, 0, 0);
        ga += 64;
        gb += 64;
        __syncthreads();  // drains vmcnt -> tiles deposited

#pragma unroll
        for (int s = 0; s < 2; ++s) {
            const int ko = s ? koff1 : koff0;
            short8 af[4], bv[4];
#pragma unroll
            for (int im = 0; im < 4; ++im)
                af[im] = *(const short8*)(abase[im] + ko);
#pragma unroll
            for (int in = 0; in < 4; ++in)
                bv[in] = *(const short8*)(bbase[in] + ko);
#pragma unroll
            for (int im = 0; im < 4; ++im)
#pragma unroll
                for (int in = 0; in < 4; ++in)
                    acc[im][in] = __builtin_amdgcn_mfma_f32_16x16x32_bf16(af[im], bv[in], acc[im][in], 0, 0, 0);
        }
        __syncthreads();  // all reads done before next iter's deposits
    }

    // ---- Epilogue (validated): C/D layout col=lrow(n), row=quad*4+reg(m)
    float bvv[4];
#pragma unroll
    for (int in = 0; in < 4; ++in)
        bvv[in] = bias[n0 + wn + in * 16 + lrow];

#pragma unroll
    for (int im = 0; im < 4; ++im) {
#pragma unroll
        for (int r = 0; r < 4; ++r) {
            float v0 = acc[im][0][r] + bvv[0];
            float v1 = acc[im][1][r] + bvv[1];
            float v2 = acc[im][2][r] + bvv[2];
            float v3 = acc[im][3][r] + bvv[3];
            float mx = fmaxf(fmaxf(v0, v1), fmaxf(v2, v3));
#pragma unroll
            for (int s = 1; s < 16; s <<= 1)
                mx = fmaxf(mx, __shfl_xor(mx, s, 64));
            float sm = __expf(v0 - mx) + __expf(v1 - mx) + __expf(v2 - mx) + __expf(v3 - mx);
#pragma unroll
            for (int s = 1; s < 16; s <<= 1)
                sm += __shfl_xor(sm, s, 64);
            if (lrow == im * 4 + r) {
                int row = wm + im * 16 + quad * 4 + r;
                redf[((w & 1) * 128 + row) * 2 + 0] = mx;  // aliases lds_a: safe post-barrier
                redf[((w & 1) * 128 + row) * 2 + 1] = sm;
            }
        }
    }
    __syncthreads();
    if (t < 128) {
        float ma = redf[t * 2 + 0],         sa = redf[t * 2 + 1];
        float mb = redf[(128 + t) * 2 + 0], sb = redf[(128 + t) * 2 + 1];
        float mm = fmaxf(ma, mb);
        float ss = sa * __expf(ma - mm) + sb * __expf(mb - mm);
        part[(size_t)blockIdx.x * M_DIM + m0 + t] = make_float2(mm, ss);
    }
}

// ---------------------------------------------------------------------------
// Fallback GEMM (round-4-validated, fp32 inputs, no ws beyond part): only
// used if ws_size can't hold xb+Wt (not the case on this harness).
// ---------------------------------------------------------------------------
__global__ __launch_bounds__(256) void gemm_lse_fb(const float* __restrict__ x,
                                                   const float* __restrict__ W,
                                                   const float* __restrict__ bias,
                                                   float2* __restrict__ part) {
    __shared__ unsigned short lds_a[128 * 32];
    __shared__ unsigned short lds_b[128 * 32];
    __shared__ float red[2][128][2];
    const int t = threadIdx.x, w = t >> 6, l = t & 63, quad = l >> 4, lrow = l & 15;
    const int m0 = blockIdx.y * 128, n0 = blockIdx.x * 128;
    const int wm = (w >> 1) * 64, wn = (w & 1) * 64;
    floatx4 acc[4][4] = {};
    const int ar = t >> 1, ah = (t & 1) * 16;
    const float* gx = x + (size_t)(m0 + ar) * K_DIM + ah;
    const int bn = t & 127, bh = (t >> 7) * 16;
    const float* gw = W + (size_t)bh * N_DIM + n0 + bn;
    for (int kt = 0; kt < K_DIM; kt += 32) {
        float4 xa[4];
#pragma unroll
        for (int q = 0; q < 4; ++q) xa[q] = *(const float4*)(gx + kt + q * 4);
        float wv[16];
#pragma unroll
        for (int j = 0; j < 16; ++j) wv[j] = gw[(size_t)(kt + j) * N_DIM];
        short8 pa0, pa1, pb0, pb1;
#pragma unroll
        for (int j = 0; j < 4; ++j) {
            pa0[j] = (short)f2bf(((const float*)&xa[0])[j]);
            pa0[j + 4] = (short)f2bf(((const float*)&xa[1])[j]);
            pa1[j] = (short)f2bf(((const float*)&xa[2])[j]);
            pa1[j + 4] = (short)f2bf(((const float*)&xa[3])[j]);
        }
#pragma unroll
        for (int j = 0; j < 8; ++j) { pb0[j] = (short)f2bf(wv[j]); pb1[j] = (short)f2bf(wv[j + 8]); }
        __syncthreads();
        *(short8*)&lds_a[ar * 32 + ah] = pa0;
        *(short8*)&lds_a[ar * 32 + ah + 8] = pa1;
        *(short8*)&lds_b[bn * 32 + bh] = pb0;
        *(short8*)&lds_b[bn * 32 + bh + 8] = pb1;
        __syncthreads();
        short8 af[4], bf[4];
#pragma unroll
        for (int im = 0; im < 4; ++im)
            af[im] = *(const short8*)((const char*)lds_a + (wm + im * 16 + lrow) * 64 + quad * 16);
#pragma unroll
        for (int in = 0; in < 4; ++in)
            bf[in] = *(const short8*)((const char*)lds_b + (wn + in * 16 + lrow) * 64 + quad * 16);
#pragma unroll
        for (int im = 0; im < 4; ++im)
#pragma unroll
            for (int in = 0; in < 4; ++in)
                acc[im][in] = __builtin_amdgcn_mfma_f32_16x16x32_bf16(af[im], bf[in], acc[im][in], 0, 0, 0);
    }
    float bvv[4];
#pragma unroll
    for (int in = 0; in < 4; ++in) bvv[in] = bias[n0 + wn + in * 16 + lrow];
#pragma unroll
    for (int im = 0; im < 4; ++im) {
#pragma unroll
        for (int r = 0; r < 4; ++r) {
            float v0 = acc[im][0][r] + bvv[0], v1 = acc[im][1][r] + bvv[1];
            float v2 = acc[im][2][r] + bvv[2], v3 = acc[im][3][r] + bvv[3];
            float mx = fmaxf(fmaxf(v0, v1), fmaxf(v2, v3));
#pragma unroll
            for (int s = 1; s < 16; s <<= 1) mx = fmaxf(mx, __shfl_xor(mx, s, 64));
            float sm = __expf(v0 - mx) + __expf(v1 - mx) + __expf(v2 - mx) + __expf(v3 - mx);
#pragma unroll
            for (int s = 1; s < 16; s <<= 1) sm += __shfl_xor(sm, s, 64);
            if (lrow == im * 4 + r) {
                int row = wm + im * 16 + quad * 4 + r;
                red[w & 1][row][0] = mx;
                red[w & 1][row][1] = sm;
            }
        }
    }
    __syncthreads();
    if (t < 128) {
        float ma = red[0][t][0], sa = red[0][t][1];
        float mb = red[1][t][0], sb = red[1][t][1];
        float mm = fmaxf(ma, mb);
        float ss = sa * __expf(ma - mm) + sb * __expf(mb - mm);
        part[(size_t)blockIdx.x * M_DIM + m0 + t] = make_float2(mm, ss);
    }
}

// ---------------------------------------------------------------------------
// Merge NBLK partials per row, logsumexp, leaky x2, erf-GELU x2. FLOAT out.
// ---------------------------------------------------------------------------
__global__ __launch_bounds__(256) void lse_final(const float2* __restrict__ part,
                                                 float* __restrict__ out) {
    const int r = blockIdx.x * 256 + threadIdx.x;
    float2 p[NBLK];
    float mm = -INFINITY;
#pragma unroll
    for (int nb = 0; nb < NBLK; ++nb) {
        p[nb] = part[(size_t)nb * M_DIM + r];
        mm = fmaxf(mm, p[nb].x);
    }
    float ss = 0.f;
#pragma unroll
    for (int nb = 0; nb < NBLK; ++nb)
        ss += p[nb].y * __expf(p[nb].x - mm);

    float z;
    if (isnan(mm)) {
        z = 12345.0f;               // tripwire A (inert when correct)
    } else if (!(ss > 0.f)) {
        z = mm;                     // tripwire B (inert when correct)
    } else {
        z = mm + logf(ss);
    }
    z = z > 0.f ? z : 0.01f * z;
    z = z > 0.f ? z : 0.01f * z;
    z = 0.5f * z * (1.f + erff(z * 0.70710678118654752f));
    z = 0.5f * z * (1.f + erff(z * 0.70710678118654752f));
    out[r] = z;
}

// ---------------------------------------------------------------------------
extern "C" void kernel_launch(void* const* d_in, const int* in_sizes, int n_in,
                              void* d_out, int out_size, void* d_ws, size_t ws_size,
                              hipStream_t stream) {
    const float* x    = (const float*)d_in[0];
    const float* W    = (const float*)d_in[1];
    const float* bias = (const float*)d_in[2];
    float* out = (float*)d_out;

    const size_t xb_bytes   = (size_t)M_DIM * K_DIM * 2;  // 134 MB
    const size_t wt_bytes   = (size_t)N_DIM * K_DIM * 2;  //   8 MB
    const size_t part_bytes = (size_t)NBLK * M_DIM * 8;   //   4 MB

    if (ws_size >= xb_bytes + wt_bytes + part_bytes) {
        unsigned short* xb = (unsigned short*)d_ws;
        unsigned short* Wt = (unsigned short*)((char*)d_ws + xb_bytes);
        float2* part = (float2*)((char*)d_ws + xb_bytes + wt_bytes);
        cvt_x<<<(int)((size_t)M_DIM * K_DIM / (8 * 256)), 256, 0, stream>>>(x, xb);
        cvt_wt<<<dim3(N_DIM / 64, K_DIM / 64), 256, 0, stream>>>(W, Wt);
        gemm_lse<<<dim3(N_DIM / 128, M_DIM / 128), 256, 0, stream>>>(xb, Wt, bias, part);
        lse_final<<<M_DIM / 256, 256, 0, stream>>>(part, out);
    } else {
        float2* part = (float2*)d_ws;
        gemm_lse_fb<<<dim3(N_DIM / 128, M_DIM / 128), 256, 0, stream>>>(x, W, bias, part);
        lse_final<<<M_DIM / 256, 256, 0, stream>>>(part, out);
    }
}